// Round 1
// baseline (1815.798 us; speedup 1.0000x reference)
//
#include <hip/hip_runtime.h>
#include <stdint.h>

#define NB 8
#define NSEQ 4096
#define DMODEL 1024
#define NH 16
#define HDIM 64
#define MROWS (NB*NSEQ)      // 32768
#define NCHUNK 32
#define CHUNKL (NSEQ/NCHUNK) // 128

typedef unsigned short u16;
typedef float f32x4 __attribute__((ext_vector_type(4)));
typedef short bf16x8 __attribute__((ext_vector_type(8)));

__device__ __forceinline__ u16 f2b(float f) {
  unsigned int u = __builtin_bit_cast(unsigned int, f);
  u = (u + 0x7FFFu + ((u >> 16) & 1u)) >> 16;
  return (u16)u;
}
__device__ __forceinline__ float b2f(u16 s) {
  unsigned int u = ((unsigned int)s) << 16;
  return __builtin_bit_cast(float, u);
}

// ---------------- weight fp32 -> bf16 conversion ----------------
__global__ void cvt_f32_bf16(const float* __restrict__ src, u16* __restrict__ dst, int n) {
  int i = blockIdx.x * blockDim.x + threadIdx.x;
  int stride = gridDim.x * blockDim.x;
  for (; i < n; i += stride) dst[i] = f2b(src[i]);
}

// ---------------- GEMM: C[M,1024] = A[M,1024] @ W[1024,1024]^T + b ----------------
// MIXA=1: A[row,k] = m[k]*x[row,k] + (1-m[k])*x[rowm1,k]  (fp32 in, cvt bf16)
// MIXA=0: A from bf16 buffer Abf.
// OUTBF=1: write bf16 to outB, else fp32 to outF.
template<int MIXA, int OUTBF>
__global__ __launch_bounds__(256) void gemm_kernel(
    const float* __restrict__ X, const u16* __restrict__ Abf,
    const float* __restrict__ mvec, const u16* __restrict__ Wb,
    const float* __restrict__ bias, float* __restrict__ outF, u16* __restrict__ outB)
{
  __shared__ __align__(16) u16 As[128*64];
  __shared__ __align__(16) u16 Bs[128*64];
  const int tid = threadIdx.x;
  const int bx = blockIdx.x, by = blockIdx.y;
  const int wave = tid >> 6, lane = tid & 63;
  const int wm = wave >> 1, wn = wave & 1;

  f32x4 acc[4][4];
#pragma unroll
  for (int i = 0; i < 4; ++i)
#pragma unroll
    for (int j = 0; j < 4; ++j) acc[i][j] = f32x4{0.f, 0.f, 0.f, 0.f};

  const int r = tid >> 1;        // staging row 0..127
  const int half = tid & 1;      // which 32-k half
  const int grow = by*128 + r;
  const int nidx = grow & (NSEQ-1);
  const int rowm1 = (nidx == 0) ? grow + (NSEQ-1) : grow - 1; // roll within batch
  const int orow = bx*128 + r;
  const int swz = (r & 7);

  for (int k0 = 0; k0 < DMODEL; k0 += 64) {
    __syncthreads();
    if (MIXA) {
#pragma unroll
      for (int j = 0; j < 4; ++j) {
        const int c = half*4 + j;
        const int kk = k0 + c*8;
        const float4 x0 = *(const float4*)(X + (size_t)grow*DMODEL + kk);
        const float4 x1 = *(const float4*)(X + (size_t)grow*DMODEL + kk + 4);
        const float4 s0 = *(const float4*)(X + (size_t)rowm1*DMODEL + kk);
        const float4 s1 = *(const float4*)(X + (size_t)rowm1*DMODEL + kk + 4);
        const float4 m0 = *(const float4*)(mvec + kk);
        const float4 m1 = *(const float4*)(mvec + kk + 4);
        bf16x8 wv;
        wv[0] = (short)f2b(m0.x*x0.x + (1.f-m0.x)*s0.x);
        wv[1] = (short)f2b(m0.y*x0.y + (1.f-m0.y)*s0.y);
        wv[2] = (short)f2b(m0.z*x0.z + (1.f-m0.z)*s0.z);
        wv[3] = (short)f2b(m0.w*x0.w + (1.f-m0.w)*s0.w);
        wv[4] = (short)f2b(m1.x*x1.x + (1.f-m1.x)*s1.x);
        wv[5] = (short)f2b(m1.y*x1.y + (1.f-m1.y)*s1.y);
        wv[6] = (short)f2b(m1.z*x1.z + (1.f-m1.z)*s1.z);
        wv[7] = (short)f2b(m1.w*x1.w + (1.f-m1.w)*s1.w);
        *(bf16x8*)&As[r*64 + ((c ^ swz)*8)] = wv;
      }
    } else {
#pragma unroll
      for (int j = 0; j < 4; ++j) {
        const int c = half*4 + j;
        bf16x8 av = *(const bf16x8*)(Abf + (size_t)grow*DMODEL + k0 + c*8);
        *(bf16x8*)&As[r*64 + ((c ^ swz)*8)] = av;
      }
    }
#pragma unroll
    for (int j = 0; j < 4; ++j) {
      const int c = half*4 + j;
      bf16x8 bv = *(const bf16x8*)(Wb + (size_t)orow*DMODEL + k0 + c*8);
      *(bf16x8*)&Bs[r*64 + ((c ^ swz)*8)] = bv;
    }
    __syncthreads();
#pragma unroll
    for (int kk = 0; kk < 2; ++kk) {
      bf16x8 af[4], bfr[4];
#pragma unroll
      for (int mi = 0; mi < 4; ++mi) {
        const int row = wm*64 + mi*16 + (lane & 15);
        const int cl = kk*4 + (lane >> 4);
        af[mi] = *(const bf16x8*)&As[row*64 + ((cl ^ (row & 7))*8)];
      }
#pragma unroll
      for (int ni = 0; ni < 4; ++ni) {
        const int row = wn*64 + ni*16 + (lane & 15);
        const int cl = kk*4 + (lane >> 4);
        bfr[ni] = *(const bf16x8*)&Bs[row*64 + ((cl ^ (row & 7))*8)];
      }
#pragma unroll
      for (int mi = 0; mi < 4; ++mi)
#pragma unroll
        for (int ni = 0; ni < 4; ++ni)
          acc[mi][ni] = __builtin_amdgcn_mfma_f32_16x16x32_bf16(af[mi], bfr[ni], acc[mi][ni], 0, 0, 0);
    }
  }

  // epilogue: C/D layout col=lane&15, row=(lane>>4)*4+reg  [m89-verified]
#pragma unroll
  for (int mi = 0; mi < 4; ++mi) {
#pragma unroll
    for (int ni = 0; ni < 4; ++ni) {
      const int gr0 = by*128 + wm*64 + mi*16 + ((lane >> 4) * 4);
      const int gc  = bx*128 + wn*64 + ni*16 + (lane & 15);
      const float bval = bias[gc];
#pragma unroll
      for (int q = 0; q < 4; ++q) {
        const float v = acc[mi][ni][q] + bval;
        const size_t oidx = (size_t)(gr0 + q)*DMODEL + gc;
        if (OUTBF) outB[oidx] = f2b(v);
        else       outF[oidx] = v;
      }
    }
  }
}

// ---------------- scan pass 1: local chunk scan, in-place wkv_local into vbuf ----------------
__global__ __launch_bounds__(64) void scan_pass1(
    const float* __restrict__ kbuf, float* vbuf,
    const float* __restrict__ w, const float* __restrict__ u,
    float* __restrict__ chunkAcc)
{
  const int bxx = blockIdx.x;
  const int c = bxx & (NCHUNK-1);
  const int bh = bxx >> 5;          // NCHUNK=32
  const int h = bh & (NH-1);
  const int b = bh >> 4;
  const int lanehd = threadIdx.x;

  const float wv = w[h*HDIM + lanehd];
  const float e = expf(wv);
  const float d = expf(-e);
  const float uv = u[h*HDIM + lanehd];

  const size_t base = ((size_t)b*NSEQ)*DMODEL + h*HDIM + lanehd;
  const int t0 = c*CHUNKL;
  float acc = 0.f;
  for (int i = 0; i < CHUNKL; ++i) {
    const size_t idx = base + (size_t)(t0 + i)*DMODEL;
    const float kf = kbuf[idx];
    const float vf = vbuf[idx];
    const float kv = kf*vf;
    acc = d*acc + kv;
    vbuf[idx] = acc + uv*kv;     // local acc + u*kv (carry added in pass 3)
  }
  chunkAcc[((size_t)bh*NCHUNK + c)*HDIM + lanehd] = acc;
}

// ---------------- scan pass 2: combine chunk carries sequentially ----------------
__global__ __launch_bounds__(64) void scan_pass2(
    const float* __restrict__ chunkAcc, float* __restrict__ carryPrev,
    const float* __restrict__ w)
{
  const int bh = blockIdx.x;
  const int h = bh & (NH-1);
  const int lanehd = threadIdx.x;
  const float wv = w[h*HDIM + lanehd];
  const float e = expf(wv);
  const float dL = expf(-e * (float)CHUNKL);   // d^CHUNKL exactly
  const size_t base = (size_t)bh*NCHUNK*HDIM + lanehd;
  float carry = 0.f;
  for (int c = 0; c < NCHUNK; ++c) {
    carryPrev[base + (size_t)c*HDIM] = carry;  // acc at end of chunk c-1
    carry = chunkAcc[base + (size_t)c*HDIM] + dL*carry;
  }
}

// ---------------- scan pass 3: carry fixup + r*wkv + LayerNorm(HD) + sigmoid gate -> h(bf16) ----------------
__global__ __launch_bounds__(64) void scan_pass3(
    const float* __restrict__ vbuf, const u16* __restrict__ rbuf,
    const u16* __restrict__ gbuf, u16* __restrict__ hbuf,
    const float* __restrict__ carryPrev, const float* __restrict__ w)
{
  const int bxx = blockIdx.x;
  const int c = bxx & (NCHUNK-1);
  const int bh = bxx >> 5;
  const int h = bh & (NH-1);
  const int b = bh >> 4;
  const int lanehd = threadIdx.x;

  const float wv = w[h*HDIM + lanehd];
  const float e = expf(wv);
  const float d = expf(-e);
  const float carry = carryPrev[((size_t)bh*NCHUNK + c)*HDIM + lanehd];

  const size_t base = ((size_t)b*NSEQ)*DMODEL + h*HDIM + lanehd;
  const int t0 = c*CHUNKL;
  float fac = d;
  for (int i = 0; i < CHUNKL; ++i) {
    const size_t idx = base + (size_t)(t0 + i)*DMODEL;
    const float wkv = vbuf[idx] + fac*carry;
    fac *= d;
    const float rw = b2f(rbuf[idx]) * wkv;
    float s1 = rw, s2 = rw*rw;
#pragma unroll
    for (int off = 32; off >= 1; off >>= 1) {
      s1 += __shfl_xor(s1, off, 64);
      s2 += __shfl_xor(s2, off, 64);
    }
    const float mean = s1 * (1.f/64.f);
    const float var = s2 * (1.f/64.f) - mean*mean;
    const float ln = (rw - mean) * rsqrtf(var + 1e-5f);
    const float gv = b2f(gbuf[idx]);
    const float sig = 1.f / (1.f + expf(-gv));
    hbuf[idx] = f2b(sig * ln);
  }
}

// ---------------- launch ----------------
extern "C" void kernel_launch(void* const* d_in, const int* in_sizes, int n_in,
                              void* d_out, int out_size, void* d_ws, size_t ws_size,
                              hipStream_t stream)
{
  const float* x   = (const float*)d_in[0];
  const float* WgW = (const float*)d_in[1];
  const float* Wgb = (const float*)d_in[2];
  const float* WrW = (const float*)d_in[3];
  const float* Wrb = (const float*)d_in[4];
  const float* WkW = (const float*)d_in[5];
  const float* Wkb = (const float*)d_in[6];
  const float* WvW = (const float*)d_in[7];
  const float* Wvb = (const float*)d_in[8];
  const float* WoW = (const float*)d_in[9];
  const float* Wob = (const float*)d_in[10];
  const float* mg  = (const float*)d_in[11];
  const float* mr  = (const float*)d_in[12];
  const float* mk  = (const float*)d_in[13];
  const float* mv  = (const float*)d_in[14];
  const float* w   = (const float*)d_in[15];
  const float* u   = (const float*)d_in[16];
  char* ws = (char*)d_ws;

  const size_t WBB = (size_t)DMODEL*DMODEL*2;
  u16* WgB = (u16*)(ws + 0*WBB);
  u16* WrB = (u16*)(ws + 1*WBB);
  u16* WkB = (u16*)(ws + 2*WBB);
  u16* WvB = (u16*)(ws + 3*WBB);
  u16* WoB = (u16*)(ws + 4*WBB);
  size_t off = 5*WBB;
  const size_t EL = (size_t)MROWS*DMODEL;
  u16* gbuf = (u16*)(ws + off);   off += EL*2;
  u16* rbuf = (u16*)(ws + off);   off += EL*2;
  float* kbuf = (float*)(ws + off); off += EL*4;
  float* vbuf = (float*)(ws + off); off += EL*4;
  u16* hbuf = (u16*)(ws + off);   off += EL*2;
  float* chunkAcc  = (float*)(ws + off); off += (size_t)NB*NH*NCHUNK*HDIM*4;
  float* carryPrev = (float*)(ws + off); off += (size_t)NB*NH*NCHUNK*HDIM*4;

  const int n1m = DMODEL*DMODEL;
  cvt_f32_bf16<<<512, 256, 0, stream>>>(WgW, WgB, n1m);
  cvt_f32_bf16<<<512, 256, 0, stream>>>(WrW, WrB, n1m);
  cvt_f32_bf16<<<512, 256, 0, stream>>>(WkW, WkB, n1m);
  cvt_f32_bf16<<<512, 256, 0, stream>>>(WvW, WvB, n1m);
  cvt_f32_bf16<<<512, 256, 0, stream>>>(WoW, WoB, n1m);

  dim3 gg(DMODEL/128, MROWS/128);
  gemm_kernel<1,1><<<gg, 256, 0, stream>>>(x, nullptr, mg, WgB, Wgb, nullptr, gbuf);
  gemm_kernel<1,1><<<gg, 256, 0, stream>>>(x, nullptr, mr, WrB, Wrb, nullptr, rbuf);
  gemm_kernel<1,0><<<gg, 256, 0, stream>>>(x, nullptr, mk, WkB, Wkb, kbuf, nullptr);
  gemm_kernel<1,0><<<gg, 256, 0, stream>>>(x, nullptr, mv, WvB, Wvb, vbuf, nullptr);

  scan_pass1<<<NB*NH*NCHUNK, 64, 0, stream>>>(kbuf, vbuf, w, u, chunkAcc);
  scan_pass2<<<NB*NH, 64, 0, stream>>>(chunkAcc, carryPrev, w);
  scan_pass3<<<NB*NH*NCHUNK, 64, 0, stream>>>(vbuf, rbuf, gbuf, hbuf, carryPrev, w);

  gemm_kernel<0,0><<<gg, 256, 0, stream>>>(nullptr, hbuf, nullptr, WoB, Wob, (float*)d_out, nullptr);
}

// Round 2
// 936.881 us; speedup vs baseline: 1.9381x; 1.9381x over previous
//
#include <hip/hip_runtime.h>
#include <stdint.h>

#define NB 8
#define NSEQ 4096
#define DMODEL 1024
#define NH 16
#define HDIM 64
#define MROWS (NB*NSEQ)      // 32768
#define NCHUNK 32
#define CHUNKL (NSEQ/NCHUNK) // 128

typedef unsigned short u16;
typedef float f32x4 __attribute__((ext_vector_type(4)));
typedef short bf16x8 __attribute__((ext_vector_type(8)));

__device__ __forceinline__ u16 f2b(float f) {
  unsigned int u = __builtin_bit_cast(unsigned int, f);
  u = (u + 0x7FFFu + ((u >> 16) & 1u)) >> 16;
  return (u16)u;
}
__device__ __forceinline__ float b2f(u16 s) {
  unsigned int u = ((unsigned int)s) << 16;
  return __builtin_bit_cast(float, u);
}

// async global->LDS, 16B per lane (dest = wave-uniform base + lane*16)
__device__ __forceinline__ void gload16(const u16* g, u16* l) {
  __builtin_amdgcn_global_load_lds(
      (const __attribute__((address_space(1))) void*)g,
      (__attribute__((address_space(3))) void*)l, 16, 0, 0);
}

// ---------------- weight fp32 -> bf16 conversion ----------------
__global__ void cvt_f32_bf16(const float* __restrict__ src, u16* __restrict__ dst, int n) {
  int i = blockIdx.x * blockDim.x + threadIdx.x;
  int stride = gridDim.x * blockDim.x;
  for (; i < n; i += stride) dst[i] = f2b(src[i]);
}

// ---------------- mix: A_p[row,k] = m_p[k]*x[row,k] + (1-m_p[k])*x[rowm1,k], 4 projections ----------------
__global__ __launch_bounds__(256) void mix4_kernel(
    const float* __restrict__ X,
    const float* __restrict__ mg, const float* __restrict__ mr,
    const float* __restrict__ mk, const float* __restrict__ mv,
    u16* __restrict__ Ag, u16* __restrict__ Ar, u16* __restrict__ Ak, u16* __restrict__ Av)
{
  const int i = blockIdx.x*256 + threadIdx.x;   // one thread = 8 elements
  const int row = i >> 7;
  const int c8 = (i & 127) << 3;
  const int nidx = row & (NSEQ-1);
  const int rowm1 = (nidx == 0) ? row + (NSEQ-1) : row - 1;  // roll within batch
  const size_t xo = (size_t)row*DMODEL + c8;
  const size_t so = (size_t)rowm1*DMODEL + c8;
  float xv[8], sv[8], mm[8];
  *(float4*)&xv[0] = *(const float4*)(X + xo);
  *(float4*)&xv[4] = *(const float4*)(X + xo + 4);
  *(float4*)&sv[0] = *(const float4*)(X + so);
  *(float4*)&sv[4] = *(const float4*)(X + so + 4);

#define DO_MIX(MP, AP) { \
    *(float4*)&mm[0] = *(const float4*)(MP + c8); \
    *(float4*)&mm[4] = *(const float4*)(MP + c8 + 4); \
    bf16x8 o; \
    _Pragma("unroll") \
    for (int j = 0; j < 8; ++j) o[j] = (short)f2b(mm[j]*xv[j] + (1.f-mm[j])*sv[j]); \
    *(bf16x8*)(AP + xo) = o; }

  DO_MIX(mg, Ag)
  DO_MIX(mr, Ar)
  DO_MIX(mk, Ak)
  DO_MIX(mv, Av)
#undef DO_MIX
}

// ---------------- GEMM: C[M,1024] = A[M,1024](bf16) @ W[1024,1024]^T(bf16) + b ----------------
// m97 structure: 128x128 tile, BK=64, global_load_lds width 16, linear LDS, 2 barriers/K-step.
template<int OUTBF>
__global__ __launch_bounds__(256) void gemm_bf16(
    const u16* __restrict__ Abf, const u16* __restrict__ Wb,
    const float* __restrict__ bias, float* __restrict__ outF, u16* __restrict__ outB)
{
  __shared__ __align__(16) u16 As[128*64];
  __shared__ __align__(16) u16 Bs[128*64];
  const int tid = threadIdx.x;
  const int bx = blockIdx.x, by = blockIdx.y;
  const int wave = tid >> 6, lane = tid & 63;
  const int wm = wave >> 1, wn = wave & 1;

  f32x4 acc[4][4];
#pragma unroll
  for (int i = 0; i < 4; ++i)
#pragma unroll
    for (int j = 0; j < 4; ++j) acc[i][j] = f32x4{0.f, 0.f, 0.f, 0.f};

  const int F0 = wave*4096 + lane*16;   // byte offset within 16KiB tile
  const size_t aRow0 = (size_t)by*128;
  const size_t bRow0 = (size_t)bx*128;

  for (int k0 = 0; k0 < DMODEL; k0 += 64) {
    __syncthreads();                    // previous tile's ds_reads done
#pragma unroll
    for (int i = 0; i < 4; ++i) {
      const int F = F0 + i*1024;        // 1KiB per wave-instruction
      const int rr = F >> 7;            // tile row (128B/row)
      const int cc = (F >> 1) & 63;     // bf16 col within BK
      gload16(Abf + (aRow0 + rr)*DMODEL + k0 + cc, (u16*)((char*)As + F));
      gload16(Wb  + (bRow0 + rr)*DMODEL + k0 + cc, (u16*)((char*)Bs + F));
    }
    __syncthreads();                    // drains vmcnt -> staged data visible
#pragma unroll
    for (int kk = 0; kk < 2; ++kk) {
      bf16x8 af[4], bfr[4];
      const int cl = kk*4 + (lane >> 4);
      const int rla = lane & 15;
#pragma unroll
      for (int mi = 0; mi < 4; ++mi) {
        const int row = wm*64 + mi*16 + rla;
        af[mi] = *(const bf16x8*)&As[row*64 + cl*8];
      }
#pragma unroll
      for (int ni = 0; ni < 4; ++ni) {
        const int row = wn*64 + ni*16 + rla;
        bfr[ni] = *(const bf16x8*)&Bs[row*64 + cl*8];
      }
#pragma unroll
      for (int mi = 0; mi < 4; ++mi)
#pragma unroll
        for (int ni = 0; ni < 4; ++ni)
          acc[mi][ni] = __builtin_amdgcn_mfma_f32_16x16x32_bf16(af[mi], bfr[ni], acc[mi][ni], 0, 0, 0);
    }
  }

  // epilogue: C/D layout col=lane&15, row=(lane>>4)*4+reg  [m89-verified]
#pragma unroll
  for (int mi = 0; mi < 4; ++mi) {
#pragma unroll
    for (int ni = 0; ni < 4; ++ni) {
      const int gr0 = by*128 + wm*64 + mi*16 + ((lane >> 4) * 4);
      const int gc  = bx*128 + wn*64 + ni*16 + (lane & 15);
      const float bval = bias[gc];
#pragma unroll
      for (int q = 0; q < 4; ++q) {
        const float v = acc[mi][ni][q] + bval;
        const size_t oidx = (size_t)(gr0 + q)*DMODEL + gc;
        if (OUTBF) outB[oidx] = f2b(v);
        else       outF[oidx] = v;
      }
    }
  }
}

// ---------------- scan pass 1: local chunk scan, in-place wkv_local into kwkv ----------------
__global__ __launch_bounds__(64) void scan_pass1(
    float* kwkv, const u16* __restrict__ vbuf,
    const float* __restrict__ w, const float* __restrict__ u,
    float* __restrict__ chunkAcc)
{
  const int bxx = blockIdx.x;
  const int c = bxx & (NCHUNK-1);
  const int bh = bxx >> 5;          // NCHUNK=32
  const int h = bh & (NH-1);
  const int b = bh >> 4;
  const int lanehd = threadIdx.x;

  const float wv = w[h*HDIM + lanehd];
  const float e = expf(wv);
  const float d = expf(-e);
  const float uv = u[h*HDIM + lanehd];

  const size_t base = ((size_t)b*NSEQ)*DMODEL + h*HDIM + lanehd;
  const int t0 = c*CHUNKL;
  float acc = 0.f;
  for (int i = 0; i < CHUNKL; ++i) {
    const size_t idx = base + (size_t)(t0 + i)*DMODEL;
    const float kf = kwkv[idx];
    const float vf = b2f(vbuf[idx]);
    const float kv = kf*vf;
    acc = d*acc + kv;
    kwkv[idx] = acc + uv*kv;     // local acc + u*kv (carry added in pass 3)
  }
  chunkAcc[((size_t)bh*NCHUNK + c)*HDIM + lanehd] = acc;
}

// ---------------- scan pass 2: combine chunk carries sequentially ----------------
__global__ __launch_bounds__(64) void scan_pass2(
    const float* __restrict__ chunkAcc, float* __restrict__ carryPrev,
    const float* __restrict__ w)
{
  const int bh = blockIdx.x;
  const int h = bh & (NH-1);
  const int lanehd = threadIdx.x;
  const float wv = w[h*HDIM + lanehd];
  const float e = expf(wv);
  const float dL = expf(-e * (float)CHUNKL);   // d^CHUNKL exactly
  const size_t base = (size_t)bh*NCHUNK*HDIM + lanehd;
  float carry = 0.f;
  for (int c = 0; c < NCHUNK; ++c) {
    carryPrev[base + (size_t)c*HDIM] = carry;  // acc at end of chunk c-1
    carry = chunkAcc[base + (size_t)c*HDIM] + dL*carry;
  }
}

// ---------------- scan pass 3: carry fixup + r*wkv + LayerNorm(HD) + sigmoid gate -> h(bf16) ----------------
__global__ __launch_bounds__(64) void scan_pass3(
    const float* __restrict__ kwkv, const u16* __restrict__ rbuf,
    const u16* __restrict__ gbuf, u16* __restrict__ hbuf,
    const float* __restrict__ carryPrev, const float* __restrict__ w)
{
  const int bxx = blockIdx.x;
  const int c = bxx & (NCHUNK-1);
  const int bh = bxx >> 5;
  const int h = bh & (NH-1);
  const int b = bh >> 4;
  const int lanehd = threadIdx.x;

  const float wv = w[h*HDIM + lanehd];
  const float e = expf(wv);
  const float d = expf(-e);
  const float carry = carryPrev[((size_t)bh*NCHUNK + c)*HDIM + lanehd];

  const size_t base = ((size_t)b*NSEQ)*DMODEL + h*HDIM + lanehd;
  const int t0 = c*CHUNKL;
  float fac = d;
  for (int i = 0; i < CHUNKL; ++i) {
    const size_t idx = base + (size_t)(t0 + i)*DMODEL;
    const float wkv = kwkv[idx] + fac*carry;
    fac *= d;
    const float rw = b2f(rbuf[idx]) * wkv;
    float s1 = rw, s2 = rw*rw;
#pragma unroll
    for (int off = 32; off >= 1; off >>= 1) {
      s1 += __shfl_xor(s1, off, 64);
      s2 += __shfl_xor(s2, off, 64);
    }
    const float mean = s1 * (1.f/64.f);
    const float var = s2 * (1.f/64.f) - mean*mean;
    const float ln = (rw - mean) * rsqrtf(var + 1e-5f);
    const float gv = b2f(gbuf[idx]);
    const float sig = 1.f / (1.f + expf(-gv));
    hbuf[idx] = f2b(sig * ln);
  }
}

// ---------------- launch ----------------
extern "C" void kernel_launch(void* const* d_in, const int* in_sizes, int n_in,
                              void* d_out, int out_size, void* d_ws, size_t ws_size,
                              hipStream_t stream)
{
  const float* x   = (const float*)d_in[0];
  const float* WgW = (const float*)d_in[1];
  const float* Wgb = (const float*)d_in[2];
  const float* WrW = (const float*)d_in[3];
  const float* Wrb = (const float*)d_in[4];
  const float* WkW = (const float*)d_in[5];
  const float* Wkb = (const float*)d_in[6];
  const float* WvW = (const float*)d_in[7];
  const float* Wvb = (const float*)d_in[8];
  const float* WoW = (const float*)d_in[9];
  const float* Wob = (const float*)d_in[10];
  const float* mg  = (const float*)d_in[11];
  const float* mr  = (const float*)d_in[12];
  const float* mk  = (const float*)d_in[13];
  const float* mv  = (const float*)d_in[14];
  const float* w   = (const float*)d_in[15];
  const float* u   = (const float*)d_in[16];
  char* ws = (char*)d_ws;

  const size_t WBB = (size_t)DMODEL*DMODEL*2;   // 2 MiB
  u16* WgB = (u16*)(ws + 0*WBB);
  u16* WrB = (u16*)(ws + 1*WBB);
  u16* WkB = (u16*)(ws + 2*WBB);
  u16* WvB = (u16*)(ws + 3*WBB);
  u16* WoB = (u16*)(ws + 4*WBB);
  size_t off = 5*WBB;
  const size_t EL = (size_t)MROWS*DMODEL;       // 33.5M elements

  // Am region: 4 x 64MiB bf16 mixed-A buffers; later aliased:
  //   kwkv (fp32, 128MiB) over [Amg,Amr]; vbuf (bf16) over Amk; hbuf over Amv.
  char* amBase = ws + off;
  u16* Amg = (u16*)(amBase);
  u16* Amr = (u16*)(amBase + EL*2);
  u16* Amk = (u16*)(amBase + EL*4);
  u16* Amv = (u16*)(amBase + EL*6);
  float* kwkv = (float*)(amBase);          // aliases Amg+Amr (free when gemm_k runs)
  u16*   vbuf = (u16*)(amBase + EL*4);     // aliases Amk (free when gemm_v runs)
  u16*   hbuf = (u16*)(amBase + EL*6);     // aliases Amv (free when pass3 runs)
  off += EL*8;
  u16* gbuf = (u16*)(ws + off);   off += EL*2;
  u16* rbuf = (u16*)(ws + off);   off += EL*2;
  float* chunkAcc  = (float*)(ws + off); off += (size_t)NB*NH*NCHUNK*HDIM*4;
  float* carryPrev = (float*)(ws + off); off += (size_t)NB*NH*NCHUNK*HDIM*4;

  const int n1m = DMODEL*DMODEL;
  cvt_f32_bf16<<<512, 256, 0, stream>>>(WgW, WgB, n1m);
  cvt_f32_bf16<<<512, 256, 0, stream>>>(WrW, WrB, n1m);
  cvt_f32_bf16<<<512, 256, 0, stream>>>(WkW, WkB, n1m);
  cvt_f32_bf16<<<512, 256, 0, stream>>>(WvW, WvB, n1m);
  cvt_f32_bf16<<<512, 256, 0, stream>>>(WoW, WoB, n1m);

  mix4_kernel<<<(int)(EL/8/256), 256, 0, stream>>>(x, mg, mr, mk, mv, Amg, Amr, Amk, Amv);

  dim3 gg(DMODEL/128, MROWS/128);
  gemm_bf16<1><<<gg, 256, 0, stream>>>(Amg, WgB, Wgb, nullptr, gbuf);
  gemm_bf16<1><<<gg, 256, 0, stream>>>(Amr, WrB, Wrb, nullptr, rbuf);
  gemm_bf16<0><<<gg, 256, 0, stream>>>(Amk, WkB, Wkb, kwkv, nullptr);   // writes over consumed Amg/Amr
  gemm_bf16<1><<<gg, 256, 0, stream>>>(Amv, WvB, Wvb, nullptr, vbuf);   // writes over consumed Amk

  scan_pass1<<<NB*NH*NCHUNK, 64, 0, stream>>>(kwkv, vbuf, w, u, chunkAcc);
  scan_pass2<<<NB*NH, 64, 0, stream>>>(chunkAcc, carryPrev, w);
  scan_pass3<<<NB*NH*NCHUNK, 64, 0, stream>>>(kwkv, rbuf, gbuf, hbuf, carryPrev, w);

  gemm_bf16<0><<<gg, 256, 0, stream>>>(hbuf, WoB, Wob, (float*)d_out, nullptr);
}

// Round 3
// 699.568 us; speedup vs baseline: 2.5956x; 1.3392x over previous
//
#include <hip/hip_runtime.h>
#include <stdint.h>

#define NB 8
#define NSEQ 4096
#define DMODEL 1024
#define NH 16
#define HDIM 64
#define MROWS (NB*NSEQ)      // 32768
#define NCHUNK 32
#define CHUNKL (NSEQ/NCHUNK) // 128

typedef unsigned short u16;
typedef float f32x4 __attribute__((ext_vector_type(4)));
typedef short bf16x8 __attribute__((ext_vector_type(8)));

__device__ __forceinline__ u16 f2b(float f) {
  unsigned int u = __builtin_bit_cast(unsigned int, f);
  u = (u + 0x7FFFu + ((u >> 16) & 1u)) >> 16;
  return (u16)u;
}
__device__ __forceinline__ float b2f(u16 s) {
  unsigned int u = ((unsigned int)s) << 16;
  return __builtin_bit_cast(float, u);
}

// async global->LDS, 16B per lane (dest = wave-uniform base + lane*16)
__device__ __forceinline__ void gload16(const void* g, void* l) {
  __builtin_amdgcn_global_load_lds(
      (const __attribute__((address_space(1))) void*)g,
      (__attribute__((address_space(3))) void*)l, 16, 0, 0);
}

// ---------------- weight fp32 -> bf16 conversion ----------------
__global__ void cvt_f32_bf16(const float* __restrict__ src, u16* __restrict__ dst, int n) {
  int i = blockIdx.x * blockDim.x + threadIdx.x;
  int stride = gridDim.x * blockDim.x;
  for (; i < n; i += stride) dst[i] = f2b(src[i]);
}

// ---------------- mix: A_p[row,k] = m_p[k]*x[row,k] + (1-m_p[k])*x[rowm1,k], 4 projections ----------------
__global__ __launch_bounds__(256) void mix4_kernel(
    const float* __restrict__ X,
    const float* __restrict__ mg, const float* __restrict__ mr,
    const float* __restrict__ mk, const float* __restrict__ mv,
    u16* __restrict__ Ag, u16* __restrict__ Ar, u16* __restrict__ Ak, u16* __restrict__ Av)
{
  const int i = blockIdx.x*256 + threadIdx.x;   // one thread = 8 elements
  const int row = i >> 7;
  const int c8 = (i & 127) << 3;
  const int nidx = row & (NSEQ-1);
  const int rowm1 = (nidx == 0) ? row + (NSEQ-1) : row - 1;  // roll within batch
  const size_t xo = (size_t)row*DMODEL + c8;
  const size_t so = (size_t)rowm1*DMODEL + c8;
  float xv[8], sv[8], mm[8];
  *(float4*)&xv[0] = *(const float4*)(X + xo);
  *(float4*)&xv[4] = *(const float4*)(X + xo + 4);
  *(float4*)&sv[0] = *(const float4*)(X + so);
  *(float4*)&sv[4] = *(const float4*)(X + so + 4);

#define DO_MIX(MP, AP) { \
    *(float4*)&mm[0] = *(const float4*)(MP + c8); \
    *(float4*)&mm[4] = *(const float4*)(MP + c8 + 4); \
    bf16x8 o; \
    _Pragma("unroll") \
    for (int j = 0; j < 8; ++j) o[j] = (short)f2b(mm[j]*xv[j] + (1.f-mm[j])*sv[j]); \
    *(bf16x8*)(AP + xo) = o; }

  DO_MIX(mg, Ag)
  DO_MIX(mr, Ar)
  DO_MIX(mk, Ak)
  DO_MIX(mv, Av)
#undef DO_MIX
}

// ---------------- GEMM 256x256 8-phase (T1+T2+T3+T4+T5), C = A @ W^T + b ----------------
// A: [32768,1024] bf16, W: [1024,1024] bf16 (row = output feature), C: [32768,1024]
// 8 waves (2M x 4N), 512 thr, BK=64 split in two kk-halves of 32 cols.
// LDS 128KiB: A[d][kk][256][32] @0, B[d][kk][256][32] @65536.
// Swizzle: 16B-slot c8 ^= (row>>1)&3, applied to global source (stage) and ds_read.
#define FENCE asm volatile("" ::: "memory")
#define BAR() { FENCE; __builtin_amdgcn_s_barrier(); FENCE; }
#define PRIO1 __builtin_amdgcn_s_setprio(1)
#define PRIO0 __builtin_amdgcn_s_setprio(0)
#define VM6 asm volatile("s_waitcnt vmcnt(6)" ::: "memory")
#define VM4 asm volatile("s_waitcnt vmcnt(4)" ::: "memory")
#define VM0 asm volatile("s_waitcnt vmcnt(0)" ::: "memory")

template<int OUTBF>
__global__ __launch_bounds__(512, 2) void gemm256(
    const u16* __restrict__ Abf, const u16* __restrict__ Wb,
    const float* __restrict__ bias, float* __restrict__ outF, u16* __restrict__ outB)
{
  __shared__ __align__(16) char lds[131072];
  const int tid = threadIdx.x;
  const int wave = tid >> 6, lane = tid & 63;
  const int wm = wave >> 2, wn = wave & 3;       // 2 x 4 waves
  const int rla = lane & 15, kgrp = lane >> 4;

  // T1: XCD-bijective swizzle. 512 blocks, xcd = wgid&7 owns by in [16*xcd, 16*xcd+16)
  const int wg = blockIdx.x;
  const int xcd = wg & 7, slot = wg >> 3;
  const int by = xcd*16 + (slot >> 2);
  const int bx = slot & 3;

  // staging source offsets (pre-swizzled): F = (wave*2+i)*1024 + lane*16
  const int F0 = (wave*2+0)*1024 + lane*16;
  const int F1 = (wave*2+1)*1024 + lane*16;
  const int r0 = F0 >> 6, r1 = F1 >> 6;
  const int c80 = ((F0 >> 4) & 3) ^ ((r0 >> 1) & 3);
  const int c81 = ((F1 >> 4) & 3) ^ ((r1 >> 1) & 3);
  const char* Ab = (const char*)Abf;
  const char* Bbp = (const char*)Wb;
  const unsigned ga0 = (unsigned)by*256*2048 + r0*2048 + c80*16;
  const unsigned ga1 = (unsigned)by*256*2048 + r1*2048 + c81*16;
  const unsigned gb0 = (unsigned)bx*256*2048 + r0*2048 + c80*16;
  const unsigned gb1 = (unsigned)bx*256*2048 + r1*2048 + c81*16;
  const int dst0 = wave*2048;
  const int dst1 = wave*2048 + 1024;

  f32x4 acc[8][4];
#pragma unroll
  for (int i = 0; i < 8; ++i)
#pragma unroll
    for (int j = 0; j < 4; ++j) acc[i][j] = f32x4{0.f,0.f,0.f,0.f};
  bf16x8 af[8], bfr[4];
  const int lane_ds = rla*64 + ((kgrp ^ ((rla>>1)&3)) << 4);

#define LDS_A(D,KK) (lds + (D)*32768 + (KK)*16384)
#define LDS_B(D,KK) (lds + 65536 + (D)*32768 + (KK)*16384)
#define LDA(D,KK) { _Pragma("unroll") for (int mi_ = 0; mi_ < 8; ++mi_) \
    af[mi_] = *(const bf16x8*)(LDS_A(D,KK) + (wm*128 + mi_*16)*64 + lane_ds); }
#define LDB(P,D,KK) { _Pragma("unroll") for (int j_ = 0; j_ < 2; ++j_) \
    bfr[(P)*2+j_] = *(const bf16x8*)(LDS_B(D,KK) + (wn*64 + ((P)*2+j_)*16)*64 + lane_ds); }
#define MM(P) { _Pragma("unroll") for (int mi_ = 0; mi_ < 8; ++mi_) { \
    acc[mi_][(P)*2+0] = __builtin_amdgcn_mfma_f32_16x16x32_bf16(af[mi_], bfr[(P)*2+0], acc[mi_][(P)*2+0], 0,0,0); \
    acc[mi_][(P)*2+1] = __builtin_amdgcn_mfma_f32_16x16x32_bf16(af[mi_], bfr[(P)*2+1], acc[mi_][(P)*2+1], 0,0,0); } }
#define STAGE(ISB, T, KK) { \
    const char* g_ = (ISB) ? Bbp : Ab; \
    const unsigned o0_ = ((ISB) ? gb0 : ga0) + (T)*128 + (KK)*64; \
    const unsigned o1_ = ((ISB) ? gb1 : ga1) + (T)*128 + (KK)*64; \
    char* l_ = (ISB) ? LDS_B((T)&1, KK) : LDS_A((T)&1, KK); \
    gload16(g_ + o0_, l_ + dst0); \
    gload16(g_ + o1_, l_ + dst1); }

  // prologue: tile0 all 4 halves, then tile1 A0,B0,A1
  STAGE(0, 0, 0); STAGE(1, 0, 0); STAGE(0, 0, 1); STAGE(1, 0, 1);
  VM4;
  STAGE(0, 1, 0); STAGE(1, 1, 0); STAGE(0, 1, 1);
  VM6;
  BAR();

  for (int i = 0; i < 8; ++i) {
    const int t1 = 2*i+1, t2 = 2*i+2, t3 = 2*i+3;
    const bool s2 = (i < 7);
    // ph1: compute tile 2i (buf0) kk0 ni01
    LDA(0,0); LDB(0,0,0); STAGE(1, t1, 1);
    BAR(); PRIO1; MM(0); PRIO0; BAR();
    // ph2: kk0 ni23
    LDB(1,0,0); if (s2) STAGE(0, t2, 0);
    BAR(); PRIO1; MM(1); PRIO0; BAR();
    // ph3: kk1 ni01
    LDA(0,1); LDB(0,0,1); if (s2) STAGE(1, t2, 0);
    BAR(); PRIO1; MM(0); PRIO0; BAR();
    // ph4: kk1 ni23  (+ counted vmcnt guarding tile 2i+1 reads)
    LDB(1,0,1); if (s2) STAGE(0, t2, 1);
    BAR(); PRIO1; MM(1); PRIO0;
    if (i == 7) { VM0; } else { VM6; }
    BAR();
    // ph5: tile 2i+1 (buf1) kk0 ni01
    LDA(1,0); LDB(0,1,0); if (s2) STAGE(1, t2, 1);
    BAR(); PRIO1; MM(0); PRIO0; BAR();
    // ph6
    LDB(1,1,0); if (s2) STAGE(0, t3, 0);
    BAR(); PRIO1; MM(1); PRIO0; BAR();
    // ph7
    LDA(1,1); LDB(0,1,1); if (s2) STAGE(1, t3, 0);
    BAR(); PRIO1; MM(0); PRIO0; BAR();
    // ph8  (+ counted vmcnt guarding next-iter tile reads)
    LDB(1,1,1); if (s2) STAGE(0, t3, 1);
    BAR(); PRIO1; MM(1); PRIO0; VM6; BAR();
  }

  // epilogue: bias + store. C/D: col=lane&15, row=(lane>>4)*4+q
  float bval[4];
#pragma unroll
  for (int ni = 0; ni < 4; ++ni) bval[ni] = bias[bx*256 + wn*64 + ni*16 + rla];
#pragma unroll
  for (int mi = 0; mi < 8; ++mi) {
#pragma unroll
    for (int ni = 0; ni < 4; ++ni) {
      const int gr0 = by*256 + wm*128 + mi*16 + kgrp*4;
      const int gc  = bx*256 + wn*64 + ni*16 + rla;
#pragma unroll
      for (int q = 0; q < 4; ++q) {
        const float v = acc[mi][ni][q] + bval[ni];
        const size_t o = (size_t)(gr0 + q)*DMODEL + gc;
        if (OUTBF) outB[o] = f2b(v);
        else       outF[o] = v;
      }
    }
  }
#undef LDS_A
#undef LDS_B
#undef LDA
#undef LDB
#undef MM
#undef STAGE
}

// ---------------- scan pass 1: local chunk scan, in-place wkv_local into kwkv ----------------
__global__ __launch_bounds__(64) void scan_pass1(
    float* kwkv, const u16* __restrict__ vbuf,
    const float* __restrict__ w, const float* __restrict__ u,
    float* __restrict__ chunkAcc)
{
  const int bxx = blockIdx.x;
  const int c = bxx & (NCHUNK-1);
  const int bh = bxx >> 5;          // NCHUNK=32
  const int h = bh & (NH-1);
  const int b = bh >> 4;
  const int lanehd = threadIdx.x;

  const float wv = w[h*HDIM + lanehd];
  const float e = expf(wv);
  const float d = expf(-e);
  const float uv = u[h*HDIM + lanehd];

  const size_t base = ((size_t)b*NSEQ)*DMODEL + h*HDIM + lanehd;
  const int t0 = c*CHUNKL;
  float acc = 0.f;
  for (int i = 0; i < CHUNKL; ++i) {
    const size_t idx = base + (size_t)(t0 + i)*DMODEL;
    const float kf = kwkv[idx];
    const float vf = b2f(vbuf[idx]);
    const float kv = kf*vf;
    acc = d*acc + kv;
    kwkv[idx] = acc + uv*kv;     // local acc + u*kv (carry added in pass 3)
  }
  chunkAcc[((size_t)bh*NCHUNK + c)*HDIM + lanehd] = acc;
}

// ---------------- scan pass 2: combine chunk carries sequentially ----------------
__global__ __launch_bounds__(64) void scan_pass2(
    const float* __restrict__ chunkAcc, float* __restrict__ carryPrev,
    const float* __restrict__ w)
{
  const int bh = blockIdx.x;
  const int h = bh & (NH-1);
  const int lanehd = threadIdx.x;
  const float wv = w[h*HDIM + lanehd];
  const float e = expf(wv);
  const float dL = expf(-e * (float)CHUNKL);   // d^CHUNKL exactly
  const size_t base = (size_t)bh*NCHUNK*HDIM + lanehd;
  float carry = 0.f;
  for (int c = 0; c < NCHUNK; ++c) {
    carryPrev[base + (size_t)c*HDIM] = carry;  // acc at end of chunk c-1
    carry = chunkAcc[base + (size_t)c*HDIM] + dL*carry;
  }
}

// ---------------- scan pass 3: carry fixup + r*wkv + LayerNorm(HD) + sigmoid gate -> h(bf16) ----------------
__global__ __launch_bounds__(64) void scan_pass3(
    const float* __restrict__ kwkv, const u16* __restrict__ rbuf,
    const u16* __restrict__ gbuf, u16* __restrict__ hbuf,
    const float* __restrict__ carryPrev, const float* __restrict__ w)
{
  const int bxx = blockIdx.x;
  const int c = bxx & (NCHUNK-1);
  const int bh = bxx >> 5;
  const int h = bh & (NH-1);
  const int b = bh >> 4;
  const int lanehd = threadIdx.x;

  const float wv = w[h*HDIM + lanehd];
  const float e = expf(wv);
  const float d = expf(-e);
  const float carry = carryPrev[((size_t)bh*NCHUNK + c)*HDIM + lanehd];

  const size_t base = ((size_t)b*NSEQ)*DMODEL + h*HDIM + lanehd;
  const int t0 = c*CHUNKL;
  float fac = d;
  for (int i = 0; i < CHUNKL; ++i) {
    const size_t idx = base + (size_t)(t0 + i)*DMODEL;
    const float wkv = kwkv[idx] + fac*carry;
    fac *= d;
    const float rw = b2f(rbuf[idx]) * wkv;
    float s1 = rw, s2 = rw*rw;
#pragma unroll
    for (int off = 32; off >= 1; off >>= 1) {
      s1 += __shfl_xor(s1, off, 64);
      s2 += __shfl_xor(s2, off, 64);
    }
    const float mean = s1 * (1.f/64.f);
    const float var = s2 * (1.f/64.f) - mean*mean;
    const float ln = (rw - mean) * rsqrtf(var + 1e-5f);
    const float gv = b2f(gbuf[idx]);
    const float sig = 1.f / (1.f + expf(-gv));
    hbuf[idx] = f2b(sig * ln);
  }
}

// ---------------- launch ----------------
extern "C" void kernel_launch(void* const* d_in, const int* in_sizes, int n_in,
                              void* d_out, int out_size, void* d_ws, size_t ws_size,
                              hipStream_t stream)
{
  const float* x   = (const float*)d_in[0];
  const float* WgW = (const float*)d_in[1];
  const float* Wgb = (const float*)d_in[2];
  const float* WrW = (const float*)d_in[3];
  const float* Wrb = (const float*)d_in[4];
  const float* WkW = (const float*)d_in[5];
  const float* Wkb = (const float*)d_in[6];
  const float* WvW = (const float*)d_in[7];
  const float* Wvb = (const float*)d_in[8];
  const float* WoW = (const float*)d_in[9];
  const float* Wob = (const float*)d_in[10];
  const float* mg  = (const float*)d_in[11];
  const float* mr  = (const float*)d_in[12];
  const float* mk  = (const float*)d_in[13];
  const float* mv  = (const float*)d_in[14];
  const float* w   = (const float*)d_in[15];
  const float* u   = (const float*)d_in[16];
  char* ws = (char*)d_ws;

  const size_t WBB = (size_t)DMODEL*DMODEL*2;   // 2 MiB
  u16* WgB = (u16*)(ws + 0*WBB);
  u16* WrB = (u16*)(ws + 1*WBB);
  u16* WkB = (u16*)(ws + 2*WBB);
  u16* WvB = (u16*)(ws + 3*WBB);
  u16* WoB = (u16*)(ws + 4*WBB);
  size_t off = 5*WBB;
  const size_t EL = (size_t)MROWS*DMODEL;       // 33.5M elements

  // Am region: 4 x 64MiB bf16 mixed-A buffers; later aliased:
  //   kwkv (fp32, 128MiB) over [Amg,Amr]; vbuf (bf16) over Amk; hbuf over Amv.
  char* amBase = ws + off;
  u16* Amg = (u16*)(amBase);
  u16* Amr = (u16*)(amBase + EL*2);
  u16* Amk = (u16*)(amBase + EL*4);
  u16* Amv = (u16*)(amBase + EL*6);
  float* kwkv = (float*)(amBase);          // aliases Amg+Amr (free when gemm_k runs)
  u16*   vbuf = (u16*)(amBase + EL*4);     // aliases Amk (free when gemm_v runs)
  u16*   hbuf = (u16*)(amBase + EL*6);     // aliases Amv (free when pass3 runs)
  off += EL*8;
  u16* gbuf = (u16*)(ws + off);   off += EL*2;
  u16* rbuf = (u16*)(ws + off);   off += EL*2;
  float* chunkAcc  = (float*)(ws + off); off += (size_t)NB*NH*NCHUNK*HDIM*4;
  float* carryPrev = (float*)(ws + off); off += (size_t)NB*NH*NCHUNK*HDIM*4;

  const int n1m = DMODEL*DMODEL;
  cvt_f32_bf16<<<512, 256, 0, stream>>>(WgW, WgB, n1m);
  cvt_f32_bf16<<<512, 256, 0, stream>>>(WrW, WrB, n1m);
  cvt_f32_bf16<<<512, 256, 0, stream>>>(WkW, WkB, n1m);
  cvt_f32_bf16<<<512, 256, 0, stream>>>(WvW, WvB, n1m);
  cvt_f32_bf16<<<512, 256, 0, stream>>>(WoW, WoB, n1m);

  mix4_kernel<<<(int)(EL/8/256), 256, 0, stream>>>(x, mg, mr, mk, mv, Amg, Amr, Amk, Amv);

  gemm256<1><<<512, 512, 0, stream>>>(Amg, WgB, Wgb, nullptr, gbuf);
  gemm256<1><<<512, 512, 0, stream>>>(Amr, WrB, Wrb, nullptr, rbuf);
  gemm256<0><<<512, 512, 0, stream>>>(Amk, WkB, Wkb, kwkv, nullptr);   // writes over consumed Amg/Amr
  gemm256<1><<<512, 512, 0, stream>>>(Amv, WvB, Wvb, nullptr, vbuf);   // writes over consumed Amk

  scan_pass1<<<NB*NH*NCHUNK, 64, 0, stream>>>(kwkv, vbuf, w, u, chunkAcc);
  scan_pass2<<<NB*NH, 64, 0, stream>>>(chunkAcc, carryPrev, w);
  scan_pass3<<<NB*NH*NCHUNK, 64, 0, stream>>>(kwkv, rbuf, gbuf, hbuf, carryPrev, w);

  gemm256<0><<<512, 512, 0, stream>>>(hbuf, WoB, Wob, (float*)d_out, nullptr);
}

// Round 4
// 580.850 us; speedup vs baseline: 3.1261x; 1.2044x over previous
//
#include <hip/hip_runtime.h>
#include <stdint.h>

#define NB 8
#define NSEQ 4096
#define DMODEL 1024
#define NH 16
#define HDIM 64
#define MROWS (NB*NSEQ)      // 32768
#define NCHUNK 64
#define CHUNKL (NSEQ/NCHUNK) // 64

typedef unsigned short u16;
typedef float f32x4 __attribute__((ext_vector_type(4)));
typedef short bf16x8 __attribute__((ext_vector_type(8)));

__device__ __forceinline__ u16 f2b(float f) {
  unsigned int u = __builtin_bit_cast(unsigned int, f);
  u = (u + 0x7FFFu + ((u >> 16) & 1u)) >> 16;
  return (u16)u;
}
__device__ __forceinline__ float b2f(u16 s) {
  unsigned int u = ((unsigned int)s) << 16;
  return __builtin_bit_cast(float, u);
}

// async global->LDS, 16B per lane (dest = wave-uniform base + lane*16)
__device__ __forceinline__ void gload16(const void* g, void* l) {
  __builtin_amdgcn_global_load_lds(
      (const __attribute__((address_space(1))) void*)g,
      (__attribute__((address_space(3))) void*)l, 16, 0, 0);
}

// ---------------- fused weight fp32 -> bf16 conversion (5 matrices) ----------------
__global__ __launch_bounds__(256) void cvt5(
    const float* __restrict__ a0, const float* __restrict__ a1,
    const float* __restrict__ a2, const float* __restrict__ a3,
    const float* __restrict__ a4,
    u16* __restrict__ b0, u16* __restrict__ b1, u16* __restrict__ b2,
    u16* __restrict__ b3, u16* __restrict__ b4)
{
  const int mat = blockIdx.x >> 7;    // 128 blocks per 1M-elem matrix
  const int blk = blockIdx.x & 127;
  const float* s; u16* d;
  switch (mat) {
    case 0: s = a0; d = b0; break;
    case 1: s = a1; d = b1; break;
    case 2: s = a2; d = b2; break;
    case 3: s = a3; d = b3; break;
    default: s = a4; d = b4; break;
  }
#pragma unroll
  for (int it = 0; it < 8; ++it) {
    const int idx = blk*8192 + it*1024 + threadIdx.x*4;
    const float4 v = *(const float4*)(s + idx);
    ushort4 o; o.x = f2b(v.x); o.y = f2b(v.y); o.z = f2b(v.z); o.w = f2b(v.w);
    *(ushort4*)(d + idx) = o;
  }
}

// ---------------- mix: A_p[row,k] = m_p[k]*x[row,k] + (1-m_p[k])*x[rowm1,k], 4 projections ----------------
__global__ __launch_bounds__(256) void mix4_kernel(
    const float* __restrict__ X,
    const float* __restrict__ mg, const float* __restrict__ mr,
    const float* __restrict__ mk, const float* __restrict__ mv,
    u16* __restrict__ Ag, u16* __restrict__ Ar, u16* __restrict__ Ak, u16* __restrict__ Av)
{
  const int i = blockIdx.x*256 + threadIdx.x;   // one thread = 8 elements
  const int row = i >> 7;
  const int c8 = (i & 127) << 3;
  const int nidx = row & (NSEQ-1);
  const int rowm1 = (nidx == 0) ? row + (NSEQ-1) : row - 1;  // roll within batch
  const size_t xo = (size_t)row*DMODEL + c8;
  const size_t so = (size_t)rowm1*DMODEL + c8;
  float xv[8], sv[8], mm[8];
  *(float4*)&xv[0] = *(const float4*)(X + xo);
  *(float4*)&xv[4] = *(const float4*)(X + xo + 4);
  *(float4*)&sv[0] = *(const float4*)(X + so);
  *(float4*)&sv[4] = *(const float4*)(X + so + 4);

#define DO_MIX(MP, AP) { \
    *(float4*)&mm[0] = *(const float4*)(MP + c8); \
    *(float4*)&mm[4] = *(const float4*)(MP + c8 + 4); \
    bf16x8 o; \
    _Pragma("unroll") \
    for (int j = 0; j < 8; ++j) o[j] = (short)f2b(mm[j]*xv[j] + (1.f-mm[j])*sv[j]); \
    *(bf16x8*)(AP + xo) = o; }

  DO_MIX(mg, Ag)
  DO_MIX(mr, Ar)
  DO_MIX(mk, Ak)
  DO_MIX(mv, Av)
#undef DO_MIX
}

// ---------------- GEMM 256x256 8-phase (T1+T2+T3+T4+T5), C = A @ W^T + b ----------------
#define FENCE asm volatile("" ::: "memory")
#define BAR() { FENCE; __builtin_amdgcn_s_barrier(); FENCE; }
#define PRIO1 __builtin_amdgcn_s_setprio(1)
#define PRIO0 __builtin_amdgcn_s_setprio(0)
#define VM6 asm volatile("s_waitcnt vmcnt(6)" ::: "memory")
#define VM4 asm volatile("s_waitcnt vmcnt(4)" ::: "memory")
#define VM0 asm volatile("s_waitcnt vmcnt(0)" ::: "memory")

template<int OUTBF>
__global__ __launch_bounds__(512, 2) void gemm256(
    const u16* __restrict__ Abf, const u16* __restrict__ Wb,
    const float* __restrict__ bias, float* __restrict__ outF, u16* __restrict__ outB)
{
  __shared__ __align__(16) char lds[131072];
  const int tid = threadIdx.x;
  const int wave = tid >> 6, lane = tid & 63;
  const int wm = wave >> 2, wn = wave & 3;       // 2 x 4 waves
  const int rla = lane & 15, kgrp = lane >> 4;

  // T1: XCD-bijective swizzle. 512 blocks, xcd = wgid&7 owns by in [16*xcd, 16*xcd+16)
  const int wg = blockIdx.x;
  const int xcd = wg & 7, slot = wg >> 3;
  const int by = xcd*16 + (slot >> 2);
  const int bx = slot & 3;

  // staging source offsets (pre-swizzled): F = (wave*2+i)*1024 + lane*16
  const int F0 = (wave*2+0)*1024 + lane*16;
  const int F1 = (wave*2+1)*1024 + lane*16;
  const int r0 = F0 >> 6, r1 = F1 >> 6;
  const int c80 = ((F0 >> 4) & 3) ^ ((r0 >> 1) & 3);
  const int c81 = ((F1 >> 4) & 3) ^ ((r1 >> 1) & 3);
  const char* Ab = (const char*)Abf;
  const char* Bbp = (const char*)Wb;
  const unsigned ga0 = (unsigned)by*256*2048 + r0*2048 + c80*16;
  const unsigned ga1 = (unsigned)by*256*2048 + r1*2048 + c81*16;
  const unsigned gb0 = (unsigned)bx*256*2048 + r0*2048 + c80*16;
  const unsigned gb1 = (unsigned)bx*256*2048 + r1*2048 + c81*16;
  const int dst0 = wave*2048;
  const int dst1 = wave*2048 + 1024;

  f32x4 acc[8][4];
#pragma unroll
  for (int i = 0; i < 8; ++i)
#pragma unroll
    for (int j = 0; j < 4; ++j) acc[i][j] = f32x4{0.f,0.f,0.f,0.f};
  bf16x8 af[8], bfr[4];
  const int lane_ds = rla*64 + ((kgrp ^ ((rla>>1)&3)) << 4);

#define LDS_A(D,KK) (lds + (D)*32768 + (KK)*16384)
#define LDS_B(D,KK) (lds + 65536 + (D)*32768 + (KK)*16384)
#define LDA(D,KK) { _Pragma("unroll") for (int mi_ = 0; mi_ < 8; ++mi_) \
    af[mi_] = *(const bf16x8*)(LDS_A(D,KK) + (wm*128 + mi_*16)*64 + lane_ds); }
#define LDB(P,D,KK) { _Pragma("unroll") for (int j_ = 0; j_ < 2; ++j_) \
    bfr[(P)*2+j_] = *(const bf16x8*)(LDS_B(D,KK) + (wn*64 + ((P)*2+j_)*16)*64 + lane_ds); }
#define MM(P) { _Pragma("unroll") for (int mi_ = 0; mi_ < 8; ++mi_) { \
    acc[mi_][(P)*2+0] = __builtin_amdgcn_mfma_f32_16x16x32_bf16(af[mi_], bfr[(P)*2+0], acc[mi_][(P)*2+0], 0,0,0); \
    acc[mi_][(P)*2+1] = __builtin_amdgcn_mfma_f32_16x16x32_bf16(af[mi_], bfr[(P)*2+1], acc[mi_][(P)*2+1], 0,0,0); } }
#define STAGE(ISB, T, KK) { \
    const char* g_ = (ISB) ? Bbp : Ab; \
    const unsigned o0_ = ((ISB) ? gb0 : ga0) + (T)*128 + (KK)*64; \
    const unsigned o1_ = ((ISB) ? gb1 : ga1) + (T)*128 + (KK)*64; \
    char* l_ = (ISB) ? LDS_B((T)&1, KK) : LDS_A((T)&1, KK); \
    gload16(g_ + o0_, l_ + dst0); \
    gload16(g_ + o1_, l_ + dst1); }

  // prologue: tile0 all 4 halves, then tile1 A0,B0,A1
  STAGE(0, 0, 0); STAGE(1, 0, 0); STAGE(0, 0, 1); STAGE(1, 0, 1);
  VM4;
  STAGE(0, 1, 0); STAGE(1, 1, 0); STAGE(0, 1, 1);
  VM6;
  BAR();

  for (int i = 0; i < 8; ++i) {
    const int t1 = 2*i+1, t2 = 2*i+2, t3 = 2*i+3;
    const bool s2 = (i < 7);
    // ph1: compute tile 2i (buf0) kk0 ni01
    LDA(0,0); LDB(0,0,0); STAGE(1, t1, 1);
    BAR(); PRIO1; MM(0); PRIO0; BAR();
    // ph2: kk0 ni23
    LDB(1,0,0); if (s2) STAGE(0, t2, 0);
    BAR(); PRIO1; MM(1); PRIO0; BAR();
    // ph3: kk1 ni01
    LDA(0,1); LDB(0,0,1); if (s2) STAGE(1, t2, 0);
    BAR(); PRIO1; MM(0); PRIO0; BAR();
    // ph4: kk1 ni23  (+ counted vmcnt guarding tile 2i+1 reads)
    LDB(1,0,1); if (s2) STAGE(0, t2, 1);
    BAR(); PRIO1; MM(1); PRIO0;
    if (i == 7) { VM0; } else { VM6; }
    BAR();
    // ph5: tile 2i+1 (buf1) kk0 ni01
    LDA(1,0); LDB(0,1,0); if (s2) STAGE(1, t2, 1);
    BAR(); PRIO1; MM(0); PRIO0; BAR();
    // ph6
    LDB(1,1,0); if (s2) STAGE(0, t3, 0);
    BAR(); PRIO1; MM(1); PRIO0; BAR();
    // ph7
    LDA(1,1); LDB(0,1,1); if (s2) STAGE(1, t3, 0);
    BAR(); PRIO1; MM(0); PRIO0; BAR();
    // ph8  (+ counted vmcnt guarding next-iter tile reads)
    LDB(1,1,1); if (s2) STAGE(0, t3, 1);
    BAR(); PRIO1; MM(1); PRIO0; VM6; BAR();
  }

  // epilogue: bias + store. C/D: col=lane&15, row=(lane>>4)*4+q
  float bval[4];
#pragma unroll
  for (int ni = 0; ni < 4; ++ni) bval[ni] = bias[bx*256 + wn*64 + ni*16 + rla];
#pragma unroll
  for (int mi = 0; mi < 8; ++mi) {
#pragma unroll
    for (int ni = 0; ni < 4; ++ni) {
      const int gr0 = by*256 + wm*128 + mi*16 + kgrp*4;
      const int gc  = bx*256 + wn*64 + ni*16 + rla;
#pragma unroll
      for (int q = 0; q < 4; ++q) {
        const float v = acc[mi][ni][q] + bval[ni];
        const size_t o = (size_t)(gr0 + q)*DMODEL + gc;
        if (OUTBF) outB[o] = f2b(v);
        else       outF[o] = v;
      }
    }
  }
#undef LDS_A
#undef LDS_B
#undef LDA
#undef LDB
#undef MM
#undef STAGE
}

// ---------------- scan pass 1: chunk-local carry compute only ----------------
// block = 256 thr = (b, chunk); lane16 group per head, 4 channels/lane.
__global__ __launch_bounds__(256) void scan_pass1(
    const u16* __restrict__ kbuf, const u16* __restrict__ vbuf,
    const float* __restrict__ w, float* __restrict__ chunkAcc)
{
  const int c = blockIdx.x & (NCHUNK-1);
  const int b = blockIdx.x >> 6;            // NCHUNK=64
  const int hh = threadIdx.x >> 4;          // head 0..15
  const int ch0 = (threadIdx.x & 15) << 2;  // channel base 0..60
  const int hch = hh*HDIM + ch0;

  float dd[4];
#pragma unroll
  for (int j = 0; j < 4; ++j) dd[j] = expf(-expf(w[hch + j]));

  const size_t base = ((size_t)b*NSEQ + (size_t)c*CHUNKL)*DMODEL + hch;
  float acc[4] = {0.f, 0.f, 0.f, 0.f};
#pragma unroll 2
  for (int i = 0; i < CHUNKL; ++i) {
    const size_t idx = base + (size_t)i*DMODEL;
    const ushort4 k4 = *(const ushort4*)(kbuf + idx);
    const ushort4 v4 = *(const ushort4*)(vbuf + idx);
    acc[0] = dd[0]*acc[0] + b2f(k4.x)*b2f(v4.x);
    acc[1] = dd[1]*acc[1] + b2f(k4.y)*b2f(v4.y);
    acc[2] = dd[2]*acc[2] + b2f(k4.z)*b2f(v4.z);
    acc[3] = dd[3]*acc[3] + b2f(k4.w)*b2f(v4.w);
  }
  float4 o; o.x = acc[0]; o.y = acc[1]; o.z = acc[2]; o.w = acc[3];
  *(float4*)&chunkAcc[((size_t)(b*NH + hh)*NCHUNK + c)*HDIM + ch0] = o;
}

// ---------------- scan pass 2: combine chunk carries sequentially ----------------
__global__ __launch_bounds__(64) void scan_pass2(
    const float* __restrict__ chunkAcc, float* __restrict__ carryPrev,
    const float* __restrict__ w)
{
  const int bh = blockIdx.x;
  const int h = bh & (NH-1);
  const int lanehd = threadIdx.x;
  const float e = expf(w[h*HDIM + lanehd]);
  const float dL = expf(-e * (float)CHUNKL);   // d^CHUNKL exactly
  const size_t base = (size_t)bh*NCHUNK*HDIM + lanehd;
  float carry = 0.f;
  for (int c = 0; c < NCHUNK; ++c) {
    carryPrev[base + (size_t)c*HDIM] = carry;  // acc entering chunk c
    carry = chunkAcc[base + (size_t)c*HDIM] + dL*carry;
  }
}

// ---------------- scan pass 3: recompute local scan + carry + u*kv + r* + LN + gate -> h(bf16) ----------------
__global__ __launch_bounds__(256) void scan_pass3(
    const u16* __restrict__ kbuf, const u16* __restrict__ vbuf,
    const u16* __restrict__ rbuf, const u16* __restrict__ gbuf,
    u16* __restrict__ hbuf, const float* __restrict__ carryPrev,
    const float* __restrict__ w, const float* __restrict__ u)
{
  const int c = blockIdx.x & (NCHUNK-1);
  const int b = blockIdx.x >> 6;
  const int hh = threadIdx.x >> 4;
  const int ch0 = (threadIdx.x & 15) << 2;
  const int hch = hh*HDIM + ch0;

  float dd[4], uv[4], carry[4], fac[4], acc[4];
#pragma unroll
  for (int j = 0; j < 4; ++j) {
    dd[j] = expf(-expf(w[hch + j]));
    uv[j] = u[hch + j];
    fac[j] = dd[j];
    acc[j] = 0.f;
  }
  const float4 cv = *(const float4*)&carryPrev[((size_t)(b*NH + hh)*NCHUNK + c)*HDIM + ch0];
  carry[0] = cv.x; carry[1] = cv.y; carry[2] = cv.z; carry[3] = cv.w;

  const size_t base = ((size_t)b*NSEQ + (size_t)c*CHUNKL)*DMODEL + hch;
#pragma unroll 2
  for (int i = 0; i < CHUNKL; ++i) {
    const size_t idx = base + (size_t)i*DMODEL;
    const ushort4 k4 = *(const ushort4*)(kbuf + idx);
    const ushort4 v4 = *(const ushort4*)(vbuf + idx);
    const ushort4 r4 = *(const ushort4*)(rbuf + idx);
    const ushort4 g4 = *(const ushort4*)(gbuf + idx);
    float rw[4];
    float s1 = 0.f, s2 = 0.f;
    {
      const float kv = b2f(k4.x)*b2f(v4.x);
      acc[0] = dd[0]*acc[0] + kv;
      const float wkv = acc[0] + fac[0]*carry[0] + uv[0]*kv;
      fac[0] *= dd[0];
      rw[0] = b2f(r4.x)*wkv; s1 += rw[0]; s2 += rw[0]*rw[0];
    }
    {
      const float kv = b2f(k4.y)*b2f(v4.y);
      acc[1] = dd[1]*acc[1] + kv;
      const float wkv = acc[1] + fac[1]*carry[1] + uv[1]*kv;
      fac[1] *= dd[1];
      rw[1] = b2f(r4.y)*wkv; s1 += rw[1]; s2 += rw[1]*rw[1];
    }
    {
      const float kv = b2f(k4.z)*b2f(v4.z);
      acc[2] = dd[2]*acc[2] + kv;
      const float wkv = acc[2] + fac[2]*carry[2] + uv[2]*kv;
      fac[2] *= dd[2];
      rw[2] = b2f(r4.z)*wkv; s1 += rw[2]; s2 += rw[2]*rw[2];
    }
    {
      const float kv = b2f(k4.w)*b2f(v4.w);
      acc[3] = dd[3]*acc[3] + kv;
      const float wkv = acc[3] + fac[3]*carry[3] + uv[3]*kv;
      fac[3] *= dd[3];
      rw[3] = b2f(r4.w)*wkv; s1 += rw[3]; s2 += rw[3]*rw[3];
    }
    // LN reduce over the 16-lane group (64 channels)
#pragma unroll
    for (int off = 8; off >= 1; off >>= 1) {
      s1 += __shfl_xor(s1, off);
      s2 += __shfl_xor(s2, off);
    }
    const float mean = s1 * (1.f/64.f);
    const float var = s2 * (1.f/64.f) - mean*mean;
    const float rstd = rsqrtf(var + 1e-5f);
    ushort4 o;
    o.x = f2b((rw[0]-mean)*rstd * (1.f/(1.f+expf(-b2f(g4.x)))));
    o.y = f2b((rw[1]-mean)*rstd * (1.f/(1.f+expf(-b2f(g4.y)))));
    o.z = f2b((rw[2]-mean)*rstd * (1.f/(1.f+expf(-b2f(g4.z)))));
    o.w = f2b((rw[3]-mean)*rstd * (1.f/(1.f+expf(-b2f(g4.w)))));
    *(ushort4*)(hbuf + idx) = o;
  }
}

// ---------------- launch ----------------
extern "C" void kernel_launch(void* const* d_in, const int* in_sizes, int n_in,
                              void* d_out, int out_size, void* d_ws, size_t ws_size,
                              hipStream_t stream)
{
  const float* x   = (const float*)d_in[0];
  const float* WgW = (const float*)d_in[1];
  const float* Wgb = (const float*)d_in[2];
  const float* WrW = (const float*)d_in[3];
  const float* Wrb = (const float*)d_in[4];
  const float* WkW = (const float*)d_in[5];
  const float* Wkb = (const float*)d_in[6];
  const float* WvW = (const float*)d_in[7];
  const float* Wvb = (const float*)d_in[8];
  const float* WoW = (const float*)d_in[9];
  const float* Wob = (const float*)d_in[10];
  const float* mg  = (const float*)d_in[11];
  const float* mr  = (const float*)d_in[12];
  const float* mk  = (const float*)d_in[13];
  const float* mv  = (const float*)d_in[14];
  const float* w   = (const float*)d_in[15];
  const float* u   = (const float*)d_in[16];
  char* ws = (char*)d_ws;

  const size_t WBB = (size_t)DMODEL*DMODEL*2;   // 2 MiB
  u16* WgB = (u16*)(ws + 0*WBB);
  u16* WrB = (u16*)(ws + 1*WBB);
  u16* WkB = (u16*)(ws + 2*WBB);
  u16* WvB = (u16*)(ws + 3*WBB);
  u16* WoB = (u16*)(ws + 4*WBB);
  size_t off = 5*WBB;
  const size_t EL = (size_t)MROWS*DMODEL;       // 33.5M elements

  // Am slots (4 x 64MiB bf16). Consumption order allows aliasing:
  //   kbuf -> slot of Amg (free after g GEMM), vbuf -> Amr slot, hbuf -> Amk slot.
  char* amBase = ws + off;
  u16* Amg = (u16*)(amBase);
  u16* Amr = (u16*)(amBase + EL*2);
  u16* Amk = (u16*)(amBase + EL*4);
  u16* Amv = (u16*)(amBase + EL*6);
  u16* kbuf = Amg;
  u16* vbuf = Amr;
  u16* hbuf = Amk;
  off += EL*8;
  u16* gbuf = (u16*)(ws + off);   off += EL*2;
  u16* rbuf = (u16*)(ws + off);   off += EL*2;
  float* chunkAcc  = (float*)(ws + off); off += (size_t)NB*NH*NCHUNK*HDIM*4;
  float* carryPrev = (float*)(ws + off); off += (size_t)NB*NH*NCHUNK*HDIM*4;

  cvt5<<<640, 256, 0, stream>>>(WgW, WrW, WkW, WvW, WoW, WgB, WrB, WkB, WvB, WoB);

  mix4_kernel<<<(int)(EL/8/256), 256, 0, stream>>>(x, mg, mr, mk, mv, Amg, Amr, Amk, Amv);

  gemm256<1><<<512, 512, 0, stream>>>(Amg, WgB, Wgb, nullptr, gbuf);
  gemm256<1><<<512, 512, 0, stream>>>(Amr, WrB, Wrb, nullptr, rbuf);
  gemm256<1><<<512, 512, 0, stream>>>(Amk, WkB, Wkb, nullptr, kbuf);   // kbuf over consumed Amg
  gemm256<1><<<512, 512, 0, stream>>>(Amv, WvB, Wvb, nullptr, vbuf);   // vbuf over consumed Amr

  scan_pass1<<<NB*NCHUNK, 256, 0, stream>>>(kbuf, vbuf, w, chunkAcc);
  scan_pass2<<<NB*NH, 64, 0, stream>>>(chunkAcc, carryPrev, w);
  scan_pass3<<<NB*NCHUNK, 256, 0, stream>>>(kbuf, vbuf, rbuf, gbuf, hbuf, carryPrev, w, u);

  gemm256<0><<<512, 512, 0, stream>>>(hbuf, WoB, Wob, (float*)d_out, nullptr);
}